// Round 1
// baseline (192.799 us; speedup 1.0000x reference)
//
#include <hip/hip_runtime.h>
#include <stdint.h>

#define N_TOK 8192
#define DIN   1024
#define DOUT  1024
#define NG    8
#define LSCALE 2.0f

typedef __attribute__((ext_vector_type(4))) float  float4v;
typedef __attribute__((ext_vector_type(8))) short  short8;
typedef short8  frag_ab;   // 8 bf16
typedef float4v frag_cd;   // 4 fp32

__device__ __forceinline__ short f2bf(float f) {
    union { float f; uint32_t u; } v; v.f = f;
    uint32_t r = v.u + 0x7fffu + ((v.u >> 16) & 1u);  // RNE
    return (short)(r >> 16);
}

__device__ __forceinline__ void load_lds16(const void* g, void* lds) {
    __builtin_amdgcn_global_load_lds(
        (const __attribute__((address_space(1))) uint32_t*)g,
        (__attribute__((address_space(3))) uint32_t*)lds,
        16, 0, 0);
}

// ---- group start offsets from sorted x_groups: starts[g] = first i with groups[i] >= g
__global__ void starts_kernel(const int* __restrict__ groups, int* __restrict__ starts) {
    int i = blockIdx.x * 256 + threadIdx.x;
    if (i > N_TOK) return;
    int cur  = (i < N_TOK) ? groups[i] : NG;
    int prev = (i == 0) ? -1 : groups[i - 1];
    for (int g = prev + 1; g <= cur; ++g) starts[g] = i;
}

// ---- x fp32 -> bf16 (8 elems/thread)
__global__ __launch_bounds__(256) void cvt_x(const float* __restrict__ x, short* __restrict__ xb) {
    size_t idx = (size_t)(blockIdx.x * 256 + threadIdx.x) * 8;
    const float4v* p = (const float4v*)(x + idx);
    float4v a = p[0], b = p[1];
    short8 o;
    o[0]=f2bf(a[0]); o[1]=f2bf(a[1]); o[2]=f2bf(a[2]); o[3]=f2bf(a[3]);
    o[4]=f2bf(b[0]); o[5]=f2bf(b[1]); o[6]=f2bf(b[2]); o[7]=f2bf(b[3]);
    *(short8*)(xb + idx) = o;
}

// ---- W_base [G][DIN][DOUT] fp32 -> Wt [G][DOUT][DIN] bf16 (64x64 LDS-tiled transpose)
__global__ __launch_bounds__(256) void cvt_w(const float* __restrict__ W, short* __restrict__ Wt) {
    __shared__ float tile[64][65];
    const int g = blockIdx.z, n0 = blockIdx.x * 64, k0 = blockIdx.y * 64;
    const int t = threadIdx.x;
    const float* Wg = W + (size_t)g * DIN * DOUT;
#pragma unroll
    for (int i = 0; i < 4; ++i) {
        int idx = i * 256 + t;
        int r = idx >> 4;           // k row 0..63
        int c = (idx & 15) * 4;     // n col
        float4v v = *(const float4v*)(Wg + (size_t)(k0 + r) * DOUT + n0 + c);
        tile[r][c+0]=v[0]; tile[r][c+1]=v[1]; tile[r][c+2]=v[2]; tile[r][c+3]=v[3];
    }
    __syncthreads();
    short* Wtg = Wt + (size_t)g * DOUT * DIN;
#pragma unroll
    for (int i = 0; i < 2; ++i) {
        int idx = i * 256 + t;
        int n  = idx >> 3;          // 0..63
        int c8 = (idx & 7) * 8;     // k chunk
        short8 o;
#pragma unroll
        for (int j = 0; j < 8; ++j) o[j] = f2bf(tile[c8 + j][n]);
        *(short8*)(Wtg + (size_t)(n0 + n) * DIN + k0 + c8) = o;
    }
}

// ---- W_B [G][16][DOUT] fp32 -> WBt [G][DOUT][32] bf16, upper 16 zero
__global__ __launch_bounds__(256) void cvt_wb(const float* __restrict__ WB, short* __restrict__ WBt) {
    int idx = blockIdx.x * 256 + threadIdx.x;   // g*1024 + n, 8192 total
    int g = idx >> 10, n = idx & 1023;
    const float* src = WB + (size_t)g * 16 * DOUT + n;
    short8 o0, o1;
#pragma unroll
    for (int r = 0; r < 8; ++r)  o0[r] = f2bf(src[(size_t)r * DOUT]);
#pragma unroll
    for (int r = 0; r < 8; ++r)  o1[r] = f2bf(src[(size_t)(r + 8) * DOUT]);
    short* dst = WBt + (size_t)idx * 32;
    *(short8*)dst        = o0;
    *(short8*)(dst + 8)  = o1;
    *(short8*)(dst + 16) = (short8)0;
    *(short8*)(dst + 24) = (short8)0;
}

// ---- a[n][r] = SCALE * x[n] . W_A[g(n)][:,r]   (wave per token, fp32 accum) -> bf16 [N][32]
__global__ __launch_bounds__(256) void lora_a_kernel(const float* __restrict__ x,
                                                     const int* __restrict__ groups,
                                                     const float* __restrict__ WA,
                                                     short* __restrict__ ab) {
    const int wid = threadIdx.x >> 6, lane = threadIdx.x & 63;
    const int n = blockIdx.x * 4 + wid;
    const int g = groups[n];
    const float* wa = WA + (size_t)g * DIN * 16;
    const float* xr = x + (size_t)n * DIN;
    float acc[16];
#pragma unroll
    for (int r = 0; r < 16; ++r) acc[r] = 0.f;
    for (int i = 0; i < DIN / 64; ++i) {
        int k = i * 64 + lane;
        float xv = xr[k];
        const float4v* w = (const float4v*)(wa + (size_t)k * 16);
        float4v w0 = w[0], w1 = w[1], w2 = w[2], w3 = w[3];
#pragma unroll
        for (int j = 0; j < 4; ++j) acc[j]      += xv * w0[j];
#pragma unroll
        for (int j = 0; j < 4; ++j) acc[4 + j]  += xv * w1[j];
#pragma unroll
        for (int j = 0; j < 4; ++j) acc[8 + j]  += xv * w2[j];
#pragma unroll
        for (int j = 0; j < 4; ++j) acc[12 + j] += xv * w3[j];
    }
#pragma unroll
    for (int off = 32; off > 0; off >>= 1)
#pragma unroll
        for (int r = 0; r < 16; ++r) acc[r] += __shfl_down(acc[r], off, 64);
    if (lane == 0) {
        short8 o0, o1;
#pragma unroll
        for (int r = 0; r < 8; ++r) o0[r] = f2bf(acc[r] * LSCALE);
#pragma unroll
        for (int r = 0; r < 8; ++r) o1[r] = f2bf(acc[r + 8] * LSCALE);
        short* dst = ab + (size_t)n * 32;
        *(short8*)dst        = o0;
        *(short8*)(dst + 8)  = o1;
        *(short8*)(dst + 16) = (short8)0;
        *(short8*)(dst + 24) = (short8)0;
    }
}

// ---- main grouped GEMM: out = x.Wt[g]^T + a.WBt[g]^T, masked store by group range
#define BM 128
#define BN 128
#define BK 64

__global__ __launch_bounds__(256, 2)
void gemm_grouped(const short* __restrict__ xb,   // [N][DIN] bf16
                  const short* __restrict__ Wt,   // [G][DOUT][DIN] bf16
                  const short* __restrict__ ab,   // [N][32] bf16 (scaled, padded)
                  const short* __restrict__ WBt,  // [G][DOUT][32] bf16 (padded)
                  const int*   __restrict__ starts,
                  float* __restrict__ out) {
    __shared__ short As[BM * BK];
    __shared__ short Bs[BN * BK];

    const int t    = threadIdx.x;
    const int lane = t & 63;
    const int wid  = t >> 6;
    const int col0 = blockIdx.x * BN;
    const int row0 = blockIdx.y * BM;
    const int wr   = (wid >> 1) * 64;   // wave row offset in tile
    const int wc   = (wid & 1) * 64;    // wave col offset
    const int m16  = lane & 15;
    const int q    = lane >> 4;

    int gbeg = 0;
    while (starts[gbeg + 1] <= row0) ++gbeg;

    for (int g = gbeg; g < NG && starts[g] < row0 + BM; ++g) {
        const int rlo = starts[g]     > row0      ? starts[g]     : row0;
        const int rhi = starts[g + 1] < row0 + BM ? starts[g + 1] : row0 + BM;
        if (rlo >= rhi) continue;

        const short* wg = Wt + (size_t)g * DOUT * DIN;

        frag_cd acc[4][4];
#pragma unroll
        for (int i = 0; i < 4; ++i)
#pragma unroll
            for (int j = 0; j < 4; ++j) { frag_cd z = {0.f,0.f,0.f,0.f}; acc[i][j] = z; }

        for (int kt = 0; kt < DIN; kt += BK) {
            // stage A: x rows [row0,row0+128), k-slice [kt,kt+64), XOR-swizzled chunks
#pragma unroll
            for (int i = 0; i < 4; ++i) {
                int L  = i * 256 + t;
                int r  = L >> 3;
                int c8 = (L & 7) ^ (r & 7);
                load_lds16(xb + (size_t)(row0 + r) * DIN + kt + c8 * 8,
                           &As[(i * 256 + wid * 64) * 8]);
            }
            // stage B: Wt rows (out cols) [col0,col0+128)
#pragma unroll
            for (int i = 0; i < 4; ++i) {
                int L  = i * 256 + t;
                int r  = L >> 3;
                int c8 = (L & 7) ^ (r & 7);
                load_lds16(wg + (size_t)(col0 + r) * DIN + kt + c8 * 8,
                           &Bs[(i * 256 + wid * 64) * 8]);
            }
            __syncthreads();

#pragma unroll
            for (int kk = 0; kk < BK; kk += 32) {
                frag_ab af[4], bf[4];
                const int ch = (kk >> 3) + q;
#pragma unroll
                for (int mi = 0; mi < 4; ++mi) {
                    int rr = wr + mi * 16 + m16;
                    af[mi] = *(const frag_ab*)&As[rr * BK + ((ch ^ (rr & 7)) << 3)];
                }
#pragma unroll
                for (int ni = 0; ni < 4; ++ni) {
                    int cc = wc + ni * 16 + m16;
                    bf[ni] = *(const frag_ab*)&Bs[cc * BK + ((ch ^ (cc & 7)) << 3)];
                }
#pragma unroll
                for (int mi = 0; mi < 4; ++mi)
#pragma unroll
                    for (int ni = 0; ni < 4; ++ni)
                        acc[mi][ni] = __builtin_amdgcn_mfma_f32_16x16x32_bf16(
                            af[mi], bf[ni], acc[mi][ni], 0, 0, 0);
            }
            __syncthreads();
        }

        // LoRA K=32 step straight from global (a is pre-scaled, zero-padded)
        {
            frag_ab af[4], bf[4];
#pragma unroll
            for (int mi = 0; mi < 4; ++mi)
                af[mi] = *(const frag_ab*)&ab[(size_t)(row0 + wr + mi * 16 + m16) * 32 + q * 8];
#pragma unroll
            for (int ni = 0; ni < 4; ++ni)
                bf[ni] = *(const frag_ab*)&WBt[((size_t)g * DOUT + col0 + wc + ni * 16 + m16) * 32 + q * 8];
#pragma unroll
            for (int mi = 0; mi < 4; ++mi)
#pragma unroll
                for (int ni = 0; ni < 4; ++ni)
                    acc[mi][ni] = __builtin_amdgcn_mfma_f32_16x16x32_bf16(
                        af[mi], bf[ni], acc[mi][ni], 0, 0, 0);
        }

        // masked epilogue: C/D layout col = lane&15, row = q*4 + reg
#pragma unroll
        for (int mi = 0; mi < 4; ++mi)
#pragma unroll
            for (int r = 0; r < 4; ++r) {
                int grow = row0 + wr + mi * 16 + q * 4 + r;
                if (grow >= rlo && grow < rhi) {
                    float* orow = out + (size_t)grow * DOUT + col0 + wc + m16;
#pragma unroll
                    for (int ni = 0; ni < 4; ++ni) orow[ni * 16] = acc[mi][ni][r];
                }
            }
    }
}

extern "C" void kernel_launch(void* const* d_in, const int* in_sizes, int n_in,
                              void* d_out, int out_size, void* d_ws, size_t ws_size,
                              hipStream_t stream) {
    const float* x      = (const float*)d_in[0];
    const int*   groups = (const int*)d_in[1];
    const float* Wb     = (const float*)d_in[2];
    const float* WA     = (const float*)d_in[3];
    const float* WB     = (const float*)d_in[4];
    float* out = (float*)d_out;

    char* ws = (char*)d_ws;
    int*   starts = (int*)ws;                                            // 36 B
    short* xb     = (short*)(ws + 1024);                                 // 16 MB
    short* Wt     = (short*)(ws + 1024 + (size_t)16 * 1024 * 1024);      // 16 MB
    short* WBt    = (short*)(ws + 1024 + (size_t)32 * 1024 * 1024);      // 512 KB
    short* ab     = (short*)(ws + 1024 + (size_t)32 * 1024 * 1024 + 512 * 1024); // 512 KB

    hipLaunchKernelGGL(starts_kernel, dim3(33), dim3(256), 0, stream, groups, starts);
    hipLaunchKernelGGL(cvt_x,   dim3(N_TOK * DIN / 8 / 256), dim3(256), 0, stream, x, xb);
    hipLaunchKernelGGL(cvt_w,   dim3(16, 16, NG), dim3(256), 0, stream, Wb, Wt);
    hipLaunchKernelGGL(cvt_wb,  dim3(NG * DOUT / 256), dim3(256), 0, stream, WB, WBt);
    hipLaunchKernelGGL(lora_a_kernel, dim3(N_TOK / 4), dim3(256), 0, stream, x, groups, WA, ab);
    hipLaunchKernelGGL(gemm_grouped, dim3(DOUT / BN, N_TOK / BM), dim3(256), 0, stream,
                       xb, Wt, ab, WBt, starts, out);
}